// Round 1
// 113.386 us; speedup vs baseline: 1.0247x; 1.0247x over previous
//
#include <hip/hip_runtime.h>

// Problem constants (from reference)
#define NUM_CLASSES 16
#define PP 7          // NUM_PARTS + 1  (output channels per head)
#define DH 12         // 2 * NUM_PARTS  (hidden channels per head)
#define C_IN 21
#define NV 8
#define NN 32              // 4 batches * 8 views
#define HW (128 * 128)     // 16384 pixels
#define PX_PER_THREAD 2
#define BLOCK 256
#define PX_PER_BLOCK (BLOCK * PX_PER_THREAD)   // 512
#define BLOCKS_PER_N (HW / PX_PER_BLOCK)       // 32

typedef float v2f __attribute__((ext_vector_type(2)));

// Fused: select class head by cls, 1x1 conv(21->12)+BN+ReLU, 1x1 conv(12->7),
// clamp at 0 (== masked max over K), plus feats identity passthrough.
// R-this: PX_PER_THREAD 4->2. Grid 512->1024 blocks => 4 blocks/CU,
// 16 waves/CU (was 8) and ~half the VGPR pressure, for better hiding of
// load latency + end-of-wave store drain. Passthrough stores interleaved
// right after each channel's layer-1 consumption (no tail store burst).
// Stores stay PLAIN cached (working set ~103 MB fits the 256 MiB L3;
// nontemporal stores regressed in R3).
__global__ __launch_bounds__(BLOCK, 4) void mvpartseg_kernel(
    const float* __restrict__ feats_in,   // (32,21,HW)
    const int*   __restrict__ cls,        // (4,1)
    const float* __restrict__ W1,         // (16,12,21)
    const float* __restrict__ b1,         // (16,12)
    const float* __restrict__ gamma1,     // (16,12)
    const float* __restrict__ beta1,      // (16,12)
    const float* __restrict__ rm1,        // (16,12)
    const float* __restrict__ rv1,        // (16,12)
    const float* __restrict__ W2,         // (16,7,12)
    const float* __restrict__ b2,         // (16,7)
    float* __restrict__ out,              // (32,7,HW)
    float* __restrict__ feats_out)        // (32,21,HW)
{
  __shared__ float w1s[C_IN][DH];   // BN-folded W1, transposed to [c][d]
  __shared__ float b1s[DH];         // BN-folded bias
  __shared__ float w2s[PP][DH];
  __shared__ float b2s[PP];

  const int t   = threadIdx.x;
  const int blk = blockIdx.x;
  const int n   = blk / BLOCKS_PER_N;       // fused batch*view index
  const int k   = cls[n / NV];              // selected class head

  // Stage effective (BN-folded) weights into LDS.
  if (t < C_IN * DH) {                       // t < 252
    const int c = t / DH, d = t - c * DH;
    const float inv = gamma1[k * DH + d] * rsqrtf(rv1[k * DH + d] + 1e-5f);
    w1s[c][d] = W1[(k * DH + d) * C_IN + c] * inv;
    if (c == 0) {
      b1s[d] = b1[k * DH + d] * inv + beta1[k * DH + d] - rm1[k * DH + d] * inv;
    }
  }
  if (t < PP * DH) {                         // t < 84
    const int p = t / DH, d = t - p * DH;
    w2s[p][d] = W2[(k * PP + p) * DH + d];
    if (d == 0) b2s[p] = b2[k * PP + p];
  }
  __syncthreads();

  const int px = (blk - n * BLOCKS_PER_N) * PX_PER_BLOCK + t * PX_PER_THREAD;
  const size_t in_base = (size_t)n * C_IN * HW + (size_t)px;

  // 1) Issue ALL channel loads back-to-back: pure load ILP on the vmcnt FIFO.
  v2f raw[C_IN];
#pragma unroll
  for (int c = 0; c < C_IN; ++c)
    raw[c] = *(const v2f*)(feats_in + in_base + (size_t)c * HW);

  // 2) Layer 1 FMAs consuming channels in load order; passthrough store for
  //    each channel issued immediately after its last use (spreads stores
  //    through the compute phase, retires the register early).
  float h[DH][PX_PER_THREAD];
#pragma unroll
  for (int d = 0; d < DH; ++d) {
    const float b = b1s[d];
    h[d][0] = b; h[d][1] = b;
  }
#pragma unroll
  for (int c = 0; c < C_IN; ++c) {
    const v2f x = raw[c];
#pragma unroll
    for (int d = 0; d < DH; ++d) {
      const float w = w1s[c][d];
      h[d][0] = fmaf(w, x.x, h[d][0]);
      h[d][1] = fmaf(w, x.y, h[d][1]);
    }
    *(v2f*)(feats_out + in_base + (size_t)c * HW) = x;
  }

  // 3) ReLU + layer 2 + clamp + output stores.
#pragma unroll
  for (int d = 0; d < DH; ++d) {
    h[d][0] = fmaxf(h[d][0], 0.f);
    h[d][1] = fmaxf(h[d][1], 0.f);
  }

  const size_t out_base = (size_t)n * PP * HW + (size_t)px;
#pragma unroll
  for (int p = 0; p < PP; ++p) {
    v2f o;
    o.x = o.y = b2s[p];
#pragma unroll
    for (int d = 0; d < DH; ++d) {
      const float w = w2s[p][d];
      o.x = fmaf(w, h[d][0], o.x);
      o.y = fmaf(w, h[d][1], o.y);
    }
    // masked max over K == clamp at 0
    o.x = fmaxf(o.x, 0.f); o.y = fmaxf(o.y, 0.f);
    *(v2f*)(out + out_base + (size_t)p * HW) = o;
  }
}

extern "C" void kernel_launch(void* const* d_in, const int* in_sizes, int n_in,
                              void* d_out, int out_size, void* d_ws, size_t ws_size,
                              hipStream_t stream) {
  const float* feats_in = (const float*)d_in[0];
  const int*   cls      = (const int*)d_in[1];
  const float* W1       = (const float*)d_in[2];
  const float* b1       = (const float*)d_in[3];
  const float* gamma1   = (const float*)d_in[4];
  const float* beta1    = (const float*)d_in[5];
  const float* rm1      = (const float*)d_in[6];
  const float* rv1      = (const float*)d_in[7];
  const float* W2       = (const float*)d_in[8];
  const float* b2       = (const float*)d_in[9];

  float* out       = (float*)d_out;                    // (32,7,HW) first
  float* feats_out = out + (size_t)NN * PP * HW;       // then (32,21,HW)

  dim3 grid(NN * BLOCKS_PER_N);   // 1024 blocks
  dim3 block(BLOCK);
  mvpartseg_kernel<<<grid, block, 0, stream>>>(
      feats_in, cls, W1, b1, gamma1, beta1, rm1, rv1, W2, b2, out, feats_out);
}